// Round 19
// baseline (256.934 us; speedup 1.0000x reference)
//
#include <hip/hip_runtime.h>
#include <math.h>

#define BB 8
#define FF 256
#define SS 1024
#define KK 16
#define ITERS 5

typedef unsigned long long ull;

// SESSION LEDGER (measured):
// R12 coop grid.sync: 94us/barrier -> multi-launch only.
// R10 64x64/wave: occupancy collapse (1088 waves), dist 147us.
// R5/R8 barrier'd 64x64/block: 124/119.6us (lockstep stalls).
// R8 cost+update last-block fusion: ~70us/iter. REVERTED.
// R13 32x32 wave-private depth-2: dist 95.0us, VALUBusy 66.75% ==
//     2048 VALU / 3072 LDS cyc per CU-chunk -> LDS-ISSUE-bound.
// R14 A-in-VGPR ping-pong: compiler spilled (567MB scratch). REVERTED.
// R16 cost RPB 16->8: neutral (~0.5us). Total best 227.7us.
// R18: dist 32x64 asymmetric wave-private tiles, 4x8 acc: 3 ds_read per
//     32 elem-ops (was 2 per 16) -> LDS/VALU ratio 2448:2048 (was 3072:
//     2048). 272 tiles/batch = 2176 waves, barrierless R13 scheduling.
//     Straddle tiles: full compute, direct+mirror always; duplicate
//     writes are bitwise-identical (same f-order) -> benign.

// ---------- wm stage 1: partial column sums of w ----------
#define ICH 8
__global__ void wm_part_kernel(const float* __restrict__ w, float* __restrict__ part) {
    int j = blockIdx.x * 256 + threadIdx.x;
    int ic = blockIdx.y, b = blockIdx.z;
    const float* wp = w + (size_t)b * SS * SS + (size_t)ic * (SS / ICH) * SS + j;
    float s = 0.f;
#pragma unroll 16
    for (int i = 0; i < SS / ICH; ++i) s += wp[(size_t)i * SS];
    part[((size_t)ic * BB + b) * SS + j] = s;
}

// ---------- d[b][i][j] = sum_f |x[b][f][i] - x[b][f][j]| ----------
#define FCD 8
__device__ __forceinline__ void async_copy16(const float* g, const float* s) {
    __builtin_amdgcn_global_load_lds((const __attribute__((address_space(1))) void*)g,
                                     (__attribute__((address_space(3))) void*)s, 16, 0, 0);
}

__global__ __launch_bounds__(128, 4) void dist_kernel(const float* __restrict__ x,
                                                      float* __restrict__ d) {
    // per wave 3072 floats: 4 bufs x [A 256 | B 512]; 2 waves = 24 KB
    __shared__ float smem[6144];
    int tid = threadIdx.x;
    int wave = tid >> 6, lane = tid & 63;
    int b = blockIdx.y;
    int w = blockIdx.x * 2 + wave;      // 0..271 tile id (32-row x 64-col)
    // tiles ordered by jt: jt block has 2jt+2 tiles (it=0..2jt+1),
    // cumulative start = jt*(jt+1)
    int jt = 0;
    while (w >= (jt + 1) * (jt + 2)) ++jt;
    int it = w - jt * (jt + 1);
    int i0 = it * 32, j0 = jt * 64;
    const float* xb = x + (size_t)b * FF * SS;
    float* db = d + (size_t)b * SS * SS;
    float* wbase = smem + wave * 3072;
    int ly = lane >> 3, lx = lane & 7;           // 8x8 lane grid, 4 rows x 8 cols each
    int sFl = lane >> 3, sTk = (lane & 7) * 4;   // A staging: 8f x 32tok, 1 inst
    int bFl = lane >> 4, bTk = (lane & 15) * 4;  // B staging: 4f x 64tok per inst

    float acc[4][8] = {};

    auto stage = [&](int c) {
        float* A = wbase + (c & 3) * 768;        // A 256 | B 512
        const float* base = xb + (size_t)c * FCD * SS;
        async_copy16(base + sFl * SS + i0 + sTk, A);                  // A f0..7
        async_copy16(base + bFl * SS + j0 + bTk, A + 256);            // B f0..3
        async_copy16(base + (4 + bFl) * SS + j0 + bTk, A + 512);      // B f4..7
    };
    auto compute = [&](int c) {
        const float* A = wbase + (c & 3) * 768;
        const float* B = A + 256;
#pragma unroll
        for (int f = 0; f < FCD; ++f) {
            float4 a = *(const float4*)(A + f * 32 + ly * 4);
            float4 b0 = *(const float4*)(B + f * 64 + lx * 8);
            float4 b1 = *(const float4*)(B + f * 64 + lx * 8 + 4);
            float av[4] = {a.x, a.y, a.z, a.w};
            float bv[8] = {b0.x, b0.y, b0.z, b0.w, b1.x, b1.y, b1.z, b1.w};
#pragma unroll
            for (int r = 0; r < 4; ++r)
#pragma unroll
                for (int cc = 0; cc < 8; ++cc)
                    acc[r][cc] += fabsf(av[r] - bv[cc]);
        }
    };

    stage(0); stage(1);                 // 6 loads in flight (depth-2)
#pragma unroll 1
    for (int c = 0; c < FF / FCD - 2; ++c) {
        // WAR: buf (c+2)&3 == (c-2)&3; compute(c-2)'s ds_reads retired
        asm volatile("s_waitcnt lgkmcnt(0)" ::: "memory");
        stage(c + 2);
        // in flight: chunks c+1,c+2 (6 loads); chunk c's 3 have landed
        asm volatile("s_waitcnt vmcnt(6)" ::: "memory");
        compute(c);
    }
    asm volatile("s_waitcnt vmcnt(3)" ::: "memory");
    compute(30);
    asm volatile("s_waitcnt vmcnt(0)" ::: "memory");
    compute(31);

    // direct: rows i0+ly*4+r, cols j0+lx*8..+7
#pragma unroll
    for (int r = 0; r < 4; ++r) {
        float4 v0 = make_float4(acc[r][0], acc[r][1], acc[r][2], acc[r][3]);
        float4 v1 = make_float4(acc[r][4], acc[r][5], acc[r][6], acc[r][7]);
        float* row = &db[(size_t)(i0 + ly * 4 + r) * SS + j0 + lx * 8];
        *(float4*)row = v0;
        *(float4*)(row + 4) = v1;
    }
    // mirror: always (straddle-tile duplicates are bitwise-identical)
#pragma unroll
    for (int cc = 0; cc < 8; ++cc) {
        float4 v = make_float4(acc[0][cc], acc[1][cc], acc[2][cc], acc[3][cc]);
        *(float4*)&db[(size_t)(j0 + lx * 8 + cc) * SS + i0 + ly * 4] = v;
    }
}

// ---------- wm finalize + topk (jax.lax.top_k) + initial assign, fused ----------
// wm > 0 strictly (means of uniform[0,1)), so float bits are order-monotonic.
__global__ __launch_bounds__(1024) void topk_assign_kernel(const float* __restrict__ part,
                                                           float* __restrict__ wm,
                                                           const float* __restrict__ d,
                                                           int* __restrict__ assign) {
    int b = blockIdx.x;
    int tid = threadIdx.x;          // == token index
    int lane = tid & 63, wv = tid >> 6;
    __shared__ ull red[16];
    __shared__ int ctr_s[KK];
    float v = 0.f;
#pragma unroll
    for (int ic = 0; ic < ICH; ++ic) v += part[((size_t)ic * BB + b) * SS + tid];
    v *= (1.0f / SS);
    wm[b * SS + tid] = v;
    ull key = (((ull)__float_as_uint(v)) << 32) | (ull)(0xFFFFFFFFu - (unsigned)tid);
    for (int k = 0; k < KK; ++k) {
        ull kk = key;
#pragma unroll
        for (int off = 32; off; off >>= 1) {
            ull o = __shfl_down(kk, off, 64);
            if (o > kk) kk = o;
        }
        if (lane == 0) red[wv] = kk;
        __syncthreads();
        if (wv == 0) {
            ull k2 = (lane < 16) ? red[lane] : 0ull;
#pragma unroll
            for (int off = 8; off; off >>= 1) {
                ull o = __shfl_down(k2, off, 64);
                if (o > k2) k2 = o;
            }
            if (lane == 0) red[0] = k2;
        }
        __syncthreads();
        ull W = red[0];
        int widx = (int)(0xFFFFFFFFu - (unsigned)(W & 0xFFFFFFFFu));
        if (tid == widx) key = 0;
        if (tid == 0) ctr_s[k] = widx;
        __syncthreads();
    }
    const float* db = d + (size_t)b * SS * SS;
    float bv = INFINITY;
    int bk = 0;
#pragma unroll
    for (int k = 0; k < KK; ++k) {
        float vv = db[(size_t)ctr_s[k] * SS + tid];
        if (vv < bv) { bv = vv; bk = k; }
    }
    assign[b * SS + tid] = bk;
}

// ---------- cost[b][i] = sum_{j: assign[j]==assign[i]} d[i][j]*wm[j] ----------
// (R16 form, measured: RPB=8, 1024 blocks, bitwise-identical topology.)
#define RPB 8
__global__ __launch_bounds__(256) void cost_kernel(const float* __restrict__ d,
                                                   const float* __restrict__ wm,
                                                   const int* __restrict__ assign,
                                                   float* __restrict__ cost) {
    int b = blockIdx.y;
    int tid = threadIdx.x;
    int lane = tid & 63, wv = tid >> 6;
    __shared__ float wmv[SS];
    __shared__ int asg[SS];
    *(float4*)&wmv[tid * 4] = *(const float4*)&wm[b * SS + tid * 4];
    *(int4*)&asg[tid * 4] = *(const int4*)&assign[b * SS + tid * 4];
    __syncthreads();
    const float* db = d + (size_t)b * SS * SS;
#pragma unroll
    for (int r = 0; r < RPB / 4; ++r) {
        int i = blockIdx.x * RPB + wv * (RPB / 4) + r;
        int my = asg[i];
        const float* drow = db + (size_t)i * SS;
        float s = 0.f;
#pragma unroll
        for (int c = 0; c < SS / 256; ++c) {      // 4 sweeps of 64 lanes x float4
            int j = c * 256 + lane * 4;
            float4 dv = *(const float4*)&drow[j];
            float4 wv4 = *(const float4*)&wmv[j];
            int4 a4 = *(const int4*)&asg[j];
            s += (a4.x == my) ? dv.x * wv4.x : 0.f;
            s += (a4.y == my) ? dv.y * wv4.y : 0.f;
            s += (a4.z == my) ? dv.z * wv4.z : 0.f;
            s += (a4.w == my) ? dv.w * wv4.w : 0.f;
        }
#pragma unroll
        for (int off = 32; off; off >>= 1) s += __shfl_down(s, off, 64);
        if (lane == 0) cost[b * SS + i] = s;
    }
}

// ---------- medoid update (+ next assign, or final gather), widened ----------
// (R4 measured-good form; 4096 threads/batch for the update phase.)
__global__ __launch_bounds__(1024) void update_assign_kernel(
        const float* __restrict__ d, const float* __restrict__ cost,
        int* __restrict__ assign, const float* __restrict__ x,
        float* __restrict__ out, int last) {
    int b = blockIdx.y;
    int q = blockIdx.x;             // quarter 0..3
    int tid = threadIdx.x;
    int lane = tid & 63, wv = tid >> 6;
    __shared__ float cost_s[SS];
    __shared__ int assign_s[SS];
    __shared__ int ctr_s[KK];
    __shared__ ull pk[4][256];
    cost_s[tid] = cost[b * SS + tid];
    assign_s[tid] = assign[b * SS + tid];
    __syncthreads();
    ull best = ~0ull;
    int k = wv;   // 16 waves, 16 clusters
    for (int c = 0; c < SS / 64; ++c) {
        int i = c * 64 + lane;
        if (assign_s[i] == k) {
            ull key = (((ull)__float_as_uint(cost_s[i])) << 32) | (unsigned)i;
            if (key < best) best = key;
        }
    }
#pragma unroll
    for (int off = 32; off; off >>= 1) {
        ull o = __shfl_down(best, off, 64);
        if (o < best) best = o;
    }
    if (lane == 0) ctr_s[k] = (best == ~0ull) ? 0 : (int)(best & 0xFFFFFFFFu);
    __syncthreads();
    const float* db = d + (size_t)b * SS * SS;
    if (!last) {
        int tok = q * 256 + (tid & 255);
        int g = tid >> 8;
        ull bk = ~0ull;
#pragma unroll
        for (int kk = 0; kk < 4; ++kk) {
            int k2 = g * 4 + kk;
            float vv = db[(size_t)ctr_s[k2] * SS + tok];
            ull key = (((ull)__float_as_uint(vv)) << 32) | (unsigned)k2;
            if (key < bk) bk = key;
        }
        pk[g][tid & 255] = bk;
        __syncthreads();
        if (tid < 256) {
            ull m = pk[0][tid];
            if (pk[1][tid] < m) m = pk[1][tid];
            if (pk[2][tid] < m) m = pk[2][tid];
            if (pk[3][tid] < m) m = pk[3][tid];
            assign[b * SS + q * 256 + tid] = (int)(m & 0xFFFFFFFFu);
        }
    } else {
        int e = q * 1024 + tid;     // FF*KK = 4096 elements total
        int f = e / KK, k2 = e % KK;
        out[((size_t)b * FF + f) * KK + k2] = x[((size_t)b * FF + f) * SS + ctr_s[k2]];
    }
}

extern "C" void kernel_launch(void* const* d_in, const int* in_sizes, int n_in,
                              void* d_out, int out_size, void* d_ws, size_t ws_size,
                              hipStream_t stream) {
    const float* x = (const float*)d_in[0];   // [B,F,S]
    const float* w = (const float*)d_in[1];   // [B,S,S]
    float* out = (float*)d_out;               // [B,F,K]

    char* ws = (char*)d_ws;
    float* d = (float*)ws;                              // B*S*S floats = 33.55 MB
    size_t off = (size_t)BB * SS * SS * sizeof(float);
    float* wm = (float*)(ws + off);   off += (size_t)BB * SS * sizeof(float);
    int* assign = (int*)(ws + off);   off += (size_t)BB * SS * sizeof(int);
    float* cost = (float*)(ws + off); off += (size_t)BB * SS * sizeof(float);
    float* part = (float*)(ws + off); // [ICH][B][S] = 256 KB (non-aliasing:
                                      // consumed by topk AFTER dist runs)

    // dist first, wm_part second — independent; wm_part backfills the tail.
    // 272 32x64 wave-tiles per batch, 2 waves (2 tiles) per block.
    dist_kernel<<<dim3(136, BB), 128, 0, stream>>>(x, d);
    wm_part_kernel<<<dim3(SS / 256, ICH, BB), 256, 0, stream>>>(w, part);
    topk_assign_kernel<<<BB, 1024, 0, stream>>>(part, wm, d, assign);
    for (int itr = 0; itr < ITERS; ++itr) {
        cost_kernel<<<dim3(SS / RPB, BB), 256, 0, stream>>>(d, wm, assign, cost);
        update_assign_kernel<<<dim3(4, BB), 1024, 0, stream>>>(d, cost, assign, x, out,
                                                               itr == ITERS - 1 ? 1 : 0);
    }
}

// Round 24
// 247.174 us; speedup vs baseline: 1.0395x; 1.0395x over previous
//
#include <hip/hip_runtime.h>
#include <math.h>

#define BB 8
#define FF 256
#define SS 1024
#define KK 16
#define ITERS 5

typedef unsigned long long ull;

// SESSION LEDGER (measured):
// R12 coop grid.sync: 94us/barrier -> multi-launch only (but validated
//     4-wave medoid scan bitwise).
// R10 64x64/wave (1088 waves): dist 147us. R18 32x64/wave (2176 waves):
//     dist 128us, occ 13.1%. R13 32x32/wave (4224 waves): dist 95us BEST.
//     LAW: wave count beats per-wave LDS efficiency here. Dist CLOSED.
// R5/R8 barrier'd: 124/119.6us. R14 A-in-VGPR: spilled, 266us.
// R8 last-block fusion: ~70us/iter (1-block update + drain). REVERTED.
// R16 cost RPB 16->8: neutral. Best total 227.7us (R17).
// R20fix: fused {medoid+assign+cost} per iter, launches 13->9; ping-pong
//     (read prev, write next) -> race-free under any dispatch order.
// R21: workspace footprint restored to R17-identical — asgB/cstB ALIAS
//     part's region (part dead after topk, stream-ordered) to rule out
//     ws overflow as the R21 container-failure cause.

// ---------- wm stage 1: partial column sums of w ----------
#define ICH 8
__global__ void wm_part_kernel(const float* __restrict__ w, float* __restrict__ part) {
    int j = blockIdx.x * 256 + threadIdx.x;
    int ic = blockIdx.y, b = blockIdx.z;
    const float* wp = w + (size_t)b * SS * SS + (size_t)ic * (SS / ICH) * SS + j;
    float s = 0.f;
#pragma unroll 16
    for (int i = 0; i < SS / ICH; ++i) s += wp[(size_t)i * SS];
    part[((size_t)ic * BB + b) * SS + j] = s;
}

// ---------- d[b][i][j] = sum_f |x[b][f][i] - x[b][f][j]| ----------
// R13-exact (measured 95.0/94.7us twice): 32x32 wave-private tiles,
// 2 waves/block, no barriers, 4224 waves = 4.1/SIMD, 4 private LDS
// buffers (depth-2 prefetch, vmcnt(4)). f ascending -> bitwise-exact d.
#define FCD 8
#define TS 32
#define NT (SS / TS)
__device__ __forceinline__ void async_copy16(const float* g, const float* s) {
    __builtin_amdgcn_global_load_lds((const __attribute__((address_space(1))) void*)g,
                                     (__attribute__((address_space(3))) void*)s, 16, 0, 0);
}

__global__ __launch_bounds__(128, 4) void dist_kernel(const float* __restrict__ x,
                                                      float* __restrict__ d) {
    __shared__ float smem[4096];   // per wave (2048): 4 bufs x [A 256 | B 256]
    int tid = threadIdx.x;
    int wave = tid >> 6, lane = tid & 63;
    int b = blockIdx.y;
    int w = blockIdx.x * 2 + wave;      // 0..527 triangular tile id (32x32 tiles)
    int it = 0, rem = w;
    while (rem >= NT - it) { rem -= NT - it; ++it; }
    int jt = it + rem;
    int i0 = it * TS, j0 = jt * TS;
    const float* xb = x + (size_t)b * FF * SS;
    float* db = d + (size_t)b * SS * SS;
    float* wbase = smem + wave * 2048;
    int ly = lane >> 3, lx = lane & 7;           // 8x8 lane grid, 4x4 each
    int sFl = lane >> 3, sTk = (lane & 7) * 4;   // staging: 8 f-rows x 32 tok/inst

    float acc[4][4] = {};

    auto stage = [&](int c) {
        float* A = wbase + (c & 3) * 512;
        const float* base = xb + ((size_t)c * FCD + sFl) * SS;
        async_copy16(base + i0 + sTk, A);          // A chunk: 8f x 32tok = 1 inst
        async_copy16(base + j0 + sTk, A + 256);    // B chunk
    };
    auto compute = [&](int c) {
        const float* A = wbase + (c & 3) * 512;
        const float* B = A + 256;
#pragma unroll
        for (int f = 0; f < FCD; ++f) {
            float4 a = *(const float4*)(A + f * 32 + ly * 4);
            float4 bb = *(const float4*)(B + f * 32 + lx * 4);
            float av[4] = {a.x, a.y, a.z, a.w};
            float bv[4] = {bb.x, bb.y, bb.z, bb.w};
#pragma unroll
            for (int r = 0; r < 4; ++r)
#pragma unroll
                for (int cc = 0; cc < 4; ++cc)
                    acc[r][cc] += fabsf(av[r] - bv[cc]);
        }
    };

    stage(0); stage(1);                 // 4 loads in flight (depth-2)
#pragma unroll 1
    for (int c = 0; c < FF / FCD - 2; ++c) {
        // WAR: buf (c+2)&3 == (c-2)&3; compute(c-2)'s ds_reads retired
        asm volatile("s_waitcnt lgkmcnt(0)" ::: "memory");
        stage(c + 2);
        // in flight: chunks c+1,c+2 (4 loads); chunk c's 2 have landed
        asm volatile("s_waitcnt vmcnt(4)" ::: "memory");
        compute(c);
    }
    asm volatile("s_waitcnt vmcnt(2)" ::: "memory");
    compute(30);
    asm volatile("s_waitcnt vmcnt(0)" ::: "memory");
    compute(31);

    // direct tile: rows i0+ly*4+r, cols j0+lx*4
#pragma unroll
    for (int r = 0; r < 4; ++r) {
        float4 v = make_float4(acc[r][0], acc[r][1], acc[r][2], acc[r][3]);
        *(float4*)&db[(size_t)(i0 + ly * 4 + r) * SS + j0 + lx * 4] = v;
    }
    if (it != jt) {
        // mirror straight from registers (d bitwise symmetric)
#pragma unroll
        for (int c = 0; c < 4; ++c) {
            float4 v = make_float4(acc[0][c], acc[1][c], acc[2][c], acc[3][c]);
            *(float4*)&db[(size_t)(j0 + lx * 4 + c) * SS + i0 + ly * 4] = v;
        }
    }
}

// ---------- wm finalize + topk (jax.lax.top_k) + initial assign, fused ----------
// wm > 0 strictly (means of uniform[0,1)), so float bits are order-monotonic.
__global__ __launch_bounds__(1024) void topk_assign_kernel(const float* __restrict__ part,
                                                           float* __restrict__ wm,
                                                           const float* __restrict__ d,
                                                           int* __restrict__ assign) {
    int b = blockIdx.x;
    int tid = threadIdx.x;          // == token index
    int lane = tid & 63, wv = tid >> 6;
    __shared__ ull red[16];
    __shared__ int ctr_s[KK];
    float v = 0.f;
#pragma unroll
    for (int ic = 0; ic < ICH; ++ic) v += part[((size_t)ic * BB + b) * SS + tid];
    v *= (1.0f / SS);
    wm[b * SS + tid] = v;
    ull key = (((ull)__float_as_uint(v)) << 32) | (ull)(0xFFFFFFFFu - (unsigned)tid);
    for (int k = 0; k < KK; ++k) {
        ull kk = key;
#pragma unroll
        for (int off = 32; off; off >>= 1) {
            ull o = __shfl_down(kk, off, 64);
            if (o > kk) kk = o;
        }
        if (lane == 0) red[wv] = kk;
        __syncthreads();
        if (wv == 0) {
            ull k2 = (lane < 16) ? red[lane] : 0ull;
#pragma unroll
            for (int off = 8; off; off >>= 1) {
                ull o = __shfl_down(k2, off, 64);
                if (o > k2) k2 = o;
            }
            if (lane == 0) red[0] = k2;
        }
        __syncthreads();
        ull W = red[0];
        int widx = (int)(0xFFFFFFFFu - (unsigned)(W & 0xFFFFFFFFu));
        if (tid == widx) key = 0;
        if (tid == 0) ctr_s[k] = widx;
        __syncthreads();
    }
    const float* db = d + (size_t)b * SS * SS;
    float bv = INFINITY;
    int bk = 0;
#pragma unroll
    for (int k = 0; k < KK; ++k) {
        float vv = db[(size_t)ctr_s[k] * SS + tid];
        if (vv < bv) { bv = vv; bk = k; }
    }
    assign[b * SS + tid] = bk;
}

// ---------- cost[b][i] = sum_{j: assign[j]==assign[i]} d[i][j]*wm[j] ----------
// (R16 measured form: RPB=8, 1024 blocks.) Used once for iteration 0.
#define RPB 8
__global__ __launch_bounds__(256) void cost_kernel(const float* __restrict__ d,
                                                   const float* __restrict__ wm,
                                                   const int* __restrict__ assign,
                                                   float* __restrict__ cost) {
    int b = blockIdx.y;
    int tid = threadIdx.x;
    int lane = tid & 63, wv = tid >> 6;
    __shared__ float wmv[SS];
    __shared__ int asg[SS];
    *(float4*)&wmv[tid * 4] = *(const float4*)&wm[b * SS + tid * 4];
    *(int4*)&asg[tid * 4] = *(const int4*)&assign[b * SS + tid * 4];
    __syncthreads();
    const float* db = d + (size_t)b * SS * SS;
#pragma unroll
    for (int r = 0; r < RPB / 4; ++r) {
        int i = blockIdx.x * RPB + wv * (RPB / 4) + r;
        int my = asg[i];
        const float* drow = db + (size_t)i * SS;
        float s = 0.f;
#pragma unroll
        for (int c = 0; c < SS / 256; ++c) {      // 4 sweeps of 64 lanes x float4
            int j = c * 256 + lane * 4;
            float4 dv = *(const float4*)&drow[j];
            float4 wv4 = *(const float4*)&wmv[j];
            int4 a4 = *(const int4*)&asg[j];
            s += (a4.x == my) ? dv.x * wv4.x : 0.f;
            s += (a4.y == my) ? dv.y * wv4.y : 0.f;
            s += (a4.z == my) ? dv.z * wv4.z : 0.f;
            s += (a4.w == my) ? dv.w * wv4.w : 0.f;
        }
#pragma unroll
        for (int off = 32; off; off >>= 1) s += __shfl_down(s, off, 64);
        if (lane == 0) cost[b * SS + i] = s;
    }
}

// ---------- R20fix: fused per-iteration kernel (iterations 1..4) ----------
// READS (assign_prev, cost_prev), WRITES (assign_next, cost_next) —
// ping-pong: no buffer both read and written in one launch -> race-free
// under any block scheduling. Each of the 128 blocks/batch REDUNDANTLY:
// (1) medoid argmin from prev cost+assign (4 waves x 4 clusters,
//     ascending scan, distinct keys -> unique min, R12-validated);
// (2) new assign for all 1024 tokens (k=0..15 packed-key min);
//     all blocks write identical bits to assign_next;
// (3) cost sweep for its 8 rows (verbatim cost body on new asg).
__global__ __launch_bounds__(256) void fused_iter_kernel(
        const float* __restrict__ d, const float* __restrict__ wm,
        const int* __restrict__ assign_prev, const float* __restrict__ cost_prev,
        int* __restrict__ assign_next, float* __restrict__ cost_next) {
    int b = blockIdx.y;
    int ib = blockIdx.x;
    int tid = threadIdx.x;
    int lane = tid & 63, wv = tid >> 6;
    __shared__ float wmv[SS];
    __shared__ int asg[SS];
    __shared__ float cost_s[SS];
    __shared__ int ctr_s[KK];
    *(float4*)&wmv[tid * 4] = *(const float4*)&wm[b * SS + tid * 4];
    *(int4*)&asg[tid * 4] = *(const int4*)&assign_prev[b * SS + tid * 4];
    *(float4*)&cost_s[tid * 4] = *(const float4*)&cost_prev[b * SS + tid * 4];
    __syncthreads();
    // (1) medoid argmin
#pragma unroll
    for (int q = 0; q < 4; ++q) {
        int k = wv + q * 4;
        ull best = ~0ull;
        for (int c = 0; c < SS / 64; ++c) {
            int i = c * 64 + lane;
            if (asg[i] == k) {
                ull key = (((ull)__float_as_uint(cost_s[i])) << 32) | (unsigned)i;
                if (key < best) best = key;
            }
        }
#pragma unroll
        for (int off = 32; off; off >>= 1) {
            ull o = __shfl_down(best, off, 64);
            if (o < best) best = o;
        }
        if (lane == 0) ctr_s[k] = (best == ~0ull) ? 0 : (int)(best & 0xFFFFFFFFu);
    }
    __syncthreads();   // ctr_s ready; all reads of prev asg done
    const float* db = d + (size_t)b * SS * SS;
    // (2) new assign: 4 tokens/thread, k ascending, packed-key min
    int na[4];
#pragma unroll
    for (int q = 0; q < 4; ++q) {
        int tok = q * 256 + tid;
        ull bk = ~0ull;
#pragma unroll
        for (int k = 0; k < KK; ++k) {
            float vv = db[(size_t)ctr_s[k] * SS + tok];
            ull key = (((ull)__float_as_uint(vv)) << 32) | (unsigned)k;
            if (key < bk) bk = key;
        }
        na[q] = (int)(bk & 0xFFFFFFFFu);
    }
    __syncthreads();   // medoid-scan reads of LDS asg complete before overwrite
#pragma unroll
    for (int q = 0; q < 4; ++q) {
        int tok = q * 256 + tid;
        asg[tok] = na[q];
        assign_next[b * SS + tok] = na[q];   // all blocks write identical bits
    }
    __syncthreads();
    // (3) cost sweep for rows ib*8 + wv*2 + r (verbatim cost body, new asg)
#pragma unroll
    for (int r = 0; r < RPB / 4; ++r) {
        int i = ib * RPB + wv * (RPB / 4) + r;
        int my = asg[i];
        const float* drow = db + (size_t)i * SS;
        float s = 0.f;
#pragma unroll
        for (int c = 0; c < SS / 256; ++c) {
            int j = c * 256 + lane * 4;
            float4 dv = *(const float4*)&drow[j];
            float4 wv4 = *(const float4*)&wmv[j];
            int4 a4 = *(const int4*)&asg[j];
            s += (a4.x == my) ? dv.x * wv4.x : 0.f;
            s += (a4.y == my) ? dv.y * wv4.y : 0.f;
            s += (a4.z == my) ? dv.z * wv4.z : 0.f;
            s += (a4.w == my) ? dv.w * wv4.w : 0.f;
        }
#pragma unroll
        for (int off = 32; off; off >>= 1) s += __shfl_down(s, off, 64);
        if (lane == 0) cost_next[b * SS + i] = s;
    }
}

// ---------- final: medoid argmin + gather (R4 measured form, last=1 path) ----------
__global__ __launch_bounds__(1024) void update_assign_kernel(
        const float* __restrict__ d, const float* __restrict__ cost,
        int* __restrict__ assign, const float* __restrict__ x,
        float* __restrict__ out, int last) {
    int b = blockIdx.y;
    int q = blockIdx.x;             // quarter 0..3
    int tid = threadIdx.x;
    int lane = tid & 63, wv = tid >> 6;
    __shared__ float cost_s[SS];
    __shared__ int assign_s[SS];
    __shared__ int ctr_s[KK];
    __shared__ ull pk[4][256];
    cost_s[tid] = cost[b * SS + tid];
    assign_s[tid] = assign[b * SS + tid];
    __syncthreads();
    ull best = ~0ull;
    int k = wv;   // 16 waves, 16 clusters
    for (int c = 0; c < SS / 64; ++c) {
        int i = c * 64 + lane;
        if (assign_s[i] == k) {
            ull key = (((ull)__float_as_uint(cost_s[i])) << 32) | (unsigned)i;
            if (key < best) best = key;
        }
    }
#pragma unroll
    for (int off = 32; off; off >>= 1) {
        ull o = __shfl_down(best, off, 64);
        if (o < best) best = o;
    }
    if (lane == 0) ctr_s[k] = (best == ~0ull) ? 0 : (int)(best & 0xFFFFFFFFu);
    __syncthreads();
    const float* db = d + (size_t)b * SS * SS;
    if (!last) {
        int tok = q * 256 + (tid & 255);
        int g = tid >> 8;
        ull bk = ~0ull;
#pragma unroll
        for (int kk = 0; kk < 4; ++kk) {
            int k2 = g * 4 + kk;
            float vv = db[(size_t)ctr_s[k2] * SS + tok];
            ull key = (((ull)__float_as_uint(vv)) << 32) | (unsigned)k2;
            if (key < bk) bk = key;
        }
        pk[g][tid & 255] = bk;
        __syncthreads();
        if (tid < 256) {
            ull m = pk[0][tid];
            if (pk[1][tid] < m) m = pk[1][tid];
            if (pk[2][tid] < m) m = pk[2][tid];
            if (pk[3][tid] < m) m = pk[3][tid];
            assign[b * SS + q * 256 + tid] = (int)(m & 0xFFFFFFFFu);
        }
    } else {
        int e = q * 1024 + tid;     // FF*KK = 4096 elements total
        int f = e / KK, k2 = e % KK;
        out[((size_t)b * FF + f) * KK + k2] = x[((size_t)b * FF + f) * SS + ctr_s[k2]];
    }
}

extern "C" void kernel_launch(void* const* d_in, const int* in_sizes, int n_in,
                              void* d_out, int out_size, void* d_ws, size_t ws_size,
                              hipStream_t stream) {
    const float* x = (const float*)d_in[0];   // [B,F,S]
    const float* w = (const float*)d_in[1];   // [B,S,S]
    float* out = (float*)d_out;               // [B,F,K]

    // R17-identical footprint. asgB/cstB ALIAS part's 256KB region:
    // part is written by wm_part (L2), read only by topk (L3); fused
    // kernels first write the aliased space at L5 — stream-ordered, safe.
    char* ws = (char*)d_ws;
    float* d = (float*)ws;                              // B*S*S floats = 33.55 MB
    size_t off = (size_t)BB * SS * SS * sizeof(float);
    float* wm = (float*)(ws + off);    off += (size_t)BB * SS * sizeof(float);
    int* asgA = (int*)(ws + off);      off += (size_t)BB * SS * sizeof(int);
    float* cstA = (float*)(ws + off);  off += (size_t)BB * SS * sizeof(float);
    float* part = (float*)(ws + off);  // [ICH][B][S] = 256 KB
    int* asgB = (int*)part;                       // first 32 KB of part
    float* cstB = (float*)(part + (size_t)BB * SS); // next 32 KB of part

    // dist first, wm_part second — independent; wm_part backfills the tail.
    // 528 triangular 32x32 wave-tiles per batch, 2 waves (2 tiles) per block.
    dist_kernel<<<dim3(264, BB), 128, 0, stream>>>(x, d);
    wm_part_kernel<<<dim3(SS / 256, ICH, BB), 256, 0, stream>>>(w, part);
    topk_assign_kernel<<<BB, 1024, 0, stream>>>(part, wm, d, asgA);
    // itr 0: plain cost from topk's assign
    cost_kernel<<<dim3(SS / RPB, BB), 256, 0, stream>>>(d, wm, asgA, cstA);
    // itrs 1..4: fused medoid+assign+cost, ping-pong A<->B
    for (int itr = 1; itr < ITERS; ++itr) {
        fused_iter_kernel<<<dim3(SS / RPB, BB), 256, 0, stream>>>(d, wm, asgA, cstA,
                                                                  asgB, cstB);
        int* ta = asgA; asgA = asgB; asgB = ta;
        float* tc = cstA; cstA = cstB; cstB = tc;
    }
    // final: medoid argmin + gather from the latest (A after 4 swaps)
    update_assign_kernel<<<dim3(4, BB), 1024, 0, stream>>>(d, cstA, asgA, x, out, 1);
}